// Round 5
// baseline (89.212 us; speedup 1.0000x reference)
//
#include <hip/hip_runtime.h>

#define BB 4
#define NN 4096
#define TI 256          // threads per block
#define IPT 4           // i's per thread
#define JB 128          // j-slices -> grid = (4,128,4) = 2048 blocks, 8 waves/SIMD
#define JLEN (NN / JB)  // 32 j's per slice
#define GRP 2           // j's per pipeline group

#if __has_builtin(__builtin_amdgcn_sqrtf)
  #define FAST_SQRT __builtin_amdgcn_sqrtf
#else
  #define FAST_SQRT sqrtf
#endif

__device__ __forceinline__ float clip1(float x) {
    return fminf(fmaxf(x, -1.0f), 1.0f);   // -> v_med3_f32
}

// ws layout (floats):
//   p4  : [BB*NN] float4 (x,y,z,r)            65536 floats
//   n2a : [BB*NN] float  (x^2+y^2+z^2)       16384 floats
//   part: [JB][BB][3][NN] float              JB*BB*3*NN floats
#define PACK_ELEMS (BB * NN)
#define N2_OFF   (PACK_ELEMS * 4)
#define PART_OFF (N2_OFF + PACK_ELEMS)

__global__ __launch_bounds__(256) void ncp_pack(
    const float* __restrict__ coords,   // [BB,NN,3]
    const float* __restrict__ radii,    // [BB,NN]
    float4* __restrict__ p4,
    float* __restrict__ n2a)
{
    const int t = blockIdx.x * 256 + threadIdx.x;
    if (t >= PACK_ELEMS) return;
    const float x = coords[t * 3 + 0];
    const float y = coords[t * 3 + 1];
    const float z = coords[t * 3 + 2];
    p4[t] = make_float4(x, y, z, radii[t]);
    n2a[t] = fmaf(z, z, fmaf(y, y, x * x));
}

// Each thread: 4 i's x one 32-j slice. Miss path per pair = 3 fma + 1 cmp via
// the dot-product identity d2 = n2i + n2j - 2*pi.pj; skip test s < 4 - n2i is
// exact enough (penalty==0 for d2>=4 >= target^2 since target<=2).
// Taken path reconstructs d2 (clamped >=0) and dx,dy,dz (dx via single fma is
// exact -> diagonal contributes exactly 0).
__global__ __launch_bounds__(TI, 8) void ncp_partial(
    const float4* __restrict__ p4,
    const float* __restrict__ n2a,
    float* __restrict__ part)
{
    const int b = blockIdx.z;
    const int s = blockIdx.y;
    const int i0 = blockIdx.x * (TI * IPT) + threadIdx.x;

    float m2x[IPT], m2y[IPT], m2z[IPT], thr[IPT], ri[IPT];
    float ax[IPT], ay[IPT], az[IPT];
    #pragma unroll
    for (int u = 0; u < IPT; ++u) {
        const int i = i0 + u * TI;
        const float4 me = p4[b * NN + i];       // coalesced
        m2x[u] = -2.0f * me.x;
        m2y[u] = -2.0f * me.y;
        m2z[u] = -2.0f * me.z;
        ri[u]  = me.w;
        thr[u] = 4.0f - n2a[b * NN + i];
        ax[u] = 0.0f; ay[u] = 0.0f; az[u] = 0.0f;
    }

    const float4* jp = p4  + b * NN + s * JLEN;
    const float*  jn = n2a + b * NN + s * JLEN;

    for (int k0 = 0; k0 < JLEN; k0 += GRP) {
        float4 c[GRP];
        float  nj[GRP];
        float  sd[GRP][IPT];
        #pragma unroll
        for (int g = 0; g < GRP; ++g) {
            c[g]  = jp[k0 + g];                 // uniform address
            nj[g] = jn[k0 + g];
        }
        #pragma unroll
        for (int g = 0; g < GRP; ++g)
            #pragma unroll
            for (int u = 0; u < IPT; ++u)
                sd[g][u] = fmaf(m2z[u], c[g].z,
                           fmaf(m2y[u], c[g].y,
                           fmaf(m2x[u], c[g].x, nj[g])));
        #pragma unroll
        for (int g = 0; g < GRP; ++g) {
            #pragma unroll
            for (int u = 0; u < IPT; ++u) {
                if (__any(sd[g][u] < thr[u])) {     // wave-uniform branch
                    const float d2   = fmaxf(sd[g][u] + (4.0f - thr[u]), 0.0f);
                    const float dist = FAST_SQRT(d2);
                    const float tgt  = fmaxf(1.0f, ri[u] + c[g].w);
                    const float p    = fmaxf(tgt - dist, 0.0f);
                    const float dx   = fmaf(-0.5f, m2x[u], -c[g].x);  // xi - xj exact
                    const float dy   = fmaf(-0.5f, m2y[u], -c[g].y);
                    const float dz   = fmaf(-0.5f, m2z[u], -c[g].z);
                    ax[u] = fmaf(p, clip1(dx), ax[u]);
                    ay[u] = fmaf(p, clip1(dy), ay[u]);
                    az[u] = fmaf(p, clip1(dz), az[u]);
                }
            }
        }
    }

    // part[((s*BB + b)*3 + comp)*NN + i] -> coalesced stores
    float* base = part + (size_t)(s * BB + b) * 3 * NN;
    #pragma unroll
    for (int u = 0; u < IPT; ++u) {
        const int i = i0 + u * TI;
        base[0 * NN + i] = ax[u];
        base[1 * NN + i] = ay[u];
        base[2 * NN + i] = az[u];
    }
}

// out[(b*NN+i)*3+c] = coords[...] + 0.1/NN * sum_s part[((s*BB+b)*3+c)*NN+i]
__global__ __launch_bounds__(256) void ncp_reduce(
    const float* __restrict__ coords,
    const float* __restrict__ part,
    float* __restrict__ out)
{
    const int t = blockIdx.x * 256 + threadIdx.x;
    if (t >= BB * 3 * NN) return;
    const int b = t / (3 * NN);
    const int r = t - b * 3 * NN;
    const int comp = r / NN;
    const int i = r - comp * NN;
    float acc = 0.0f;
    #pragma unroll 8
    for (int s = 0; s < JB; ++s)
        acc += part[((size_t)(s * BB + b) * 3 + comp) * NN + i];
    const int o = (b * NN + i) * 3 + comp;
    out[o] = fmaf(0.1f / (float)NN, acc, coords[o]);
}

// Fallback if ws too small (LDS staging version, correctness backstop).
__global__ __launch_bounds__(TI) void ncp_direct(
    const float* __restrict__ coords,
    const float* __restrict__ radii,
    float* __restrict__ out)
{
    __shared__ float4 jt[TI];
    const int b = blockIdx.z;
    const int i = blockIdx.x * TI + threadIdx.x;

    const float xi = coords[(b * NN + i) * 3 + 0];
    const float yi = coords[(b * NN + i) * 3 + 1];
    const float zi = coords[(b * NN + i) * 3 + 2];
    const float ri = radii[b * NN + i];

    float ax = 0.0f, ay = 0.0f, az = 0.0f;

    for (int jc = 0; jc < NN; jc += TI) {
        const int jj = jc + threadIdx.x;
        __syncthreads();
        jt[threadIdx.x] = make_float4(coords[(b * NN + jj) * 3 + 0],
                                      coords[(b * NN + jj) * 3 + 1],
                                      coords[(b * NN + jj) * 3 + 2],
                                      radii[b * NN + jj]);
        __syncthreads();
        #pragma unroll 4
        for (int k = 0; k < TI; ++k) {
            const float4 c = jt[k];
            const float dx = xi - c.x;
            const float dy = yi - c.y;
            const float dz = zi - c.z;
            const float d2 = fmaf(dx, dx, fmaf(dy, dy, dz * dz));
            if (__any(d2 < 4.0f)) {
                const float dist = FAST_SQRT(d2);
                const float tgt = fmaxf(1.0f, ri + c.w);
                const float p = fmaxf(tgt - dist, 0.0f);
                ax = fmaf(p, clip1(dx), ax);
                ay = fmaf(p, clip1(dy), ay);
                az = fmaf(p, clip1(dz), az);
            }
        }
    }

    const int o = (b * NN + i) * 3;
    const float sc = 0.1f / (float)NN;
    out[o + 0] = fmaf(sc, ax, coords[o + 0]);
    out[o + 1] = fmaf(sc, ay, coords[o + 1]);
    out[o + 2] = fmaf(sc, az, coords[o + 2]);
}

extern "C" void kernel_launch(void* const* d_in, const int* in_sizes, int n_in,
                              void* d_out, int out_size, void* d_ws, size_t ws_size,
                              hipStream_t stream) {
    const float* coords = (const float*)d_in[0];
    const float* radii  = (const float*)d_in[1];
    float* out = (float*)d_out;
    const size_t part_floats = (size_t)JB * BB * 3 * NN;
    const size_t need = (PART_OFF + part_floats) * sizeof(float);

    if (ws_size >= need) {
        float4* p4  = (float4*)d_ws;
        float* n2a  = (float*)d_ws + N2_OFF;
        float* part = (float*)d_ws + PART_OFF;
        ncp_pack<<<(PACK_ELEMS + 255) / 256, 256, 0, stream>>>(coords, radii, p4, n2a);
        ncp_partial<<<dim3(NN / (TI * IPT), JB, BB), TI, 0, stream>>>(p4, n2a, part);
        ncp_reduce<<<(BB * 3 * NN + 255) / 256, 256, 0, stream>>>(coords, part, out);
    } else {
        ncp_direct<<<dim3(NN / TI, 1, BB), TI, 0, stream>>>(coords, radii, out);
    }
}

// Round 6
// 83.801 us; speedup vs baseline: 1.0646x; 1.0646x over previous
//
#include <hip/hip_runtime.h>

#define BB 4
#define NN 4096
#define WPB 16            // waves per block
#define TPB (WPB * 64)    // 1024 threads
#define JPW (NN / WPB)    // 256 j's per wave
#define GRP 4             // prefetch depth (j's per group)

#if __has_builtin(__builtin_amdgcn_sqrtf)
  #define FAST_SQRT __builtin_amdgcn_sqrtf
#else
  #define FAST_SQRT sqrtf
#endif

__device__ __forceinline__ float clip1(float x) {
    return fminf(fmaxf(x, -1.0f), 1.0f);   // -> v_med3_f32
}

// ws layout (floats): p4 [BB*NN] float4 (x,y,z,r); n2a [BB*NN] float
#define PACK_ELEMS (BB * NN)
#define N2_OFF (PACK_ELEMS * 4)

__global__ __launch_bounds__(256) void ncp_pack(
    const float* __restrict__ coords,   // [BB,NN,3]
    const float* __restrict__ radii,    // [BB,NN]
    float4* __restrict__ p4,
    float* __restrict__ n2a)
{
    const int t = blockIdx.x * 256 + threadIdx.x;
    if (t >= PACK_ELEMS) return;
    const float x = coords[t * 3 + 0];
    const float y = coords[t * 3 + 1];
    const float z = coords[t * 3 + 2];
    p4[t] = make_float4(x, y, z, radii[t]);
    n2a[t] = fmaf(z, z, fmaf(y, y, x * x));
}

// One block per (b, 64-i chunk). lane -> i, wave -> 256-j slice (uniform base
// via readfirstlane => scalar loads). Early-out exact: target<=2, d2>=4 -> 0.
// Cross-wave LDS reduce, epilogue writes out directly. No part buffer.
__global__ __launch_bounds__(TPB, 4) void ncp_fused(
    const float4* __restrict__ p4,
    const float* __restrict__ n2a,
    const float* __restrict__ coords,
    float* __restrict__ out)
{
    __shared__ float sh[WPB][3][64];    // 12 KB

    const int b = blockIdx.z;
    const int ibase = blockIdx.x * 64;
    const int lane = threadIdx.x & 63;
    const int w = threadIdx.x >> 6;
    const int i = ibase + lane;

    const float4 me = p4[b * NN + i];           // coalesced per-lane
    const float n2i = n2a[b * NN + i];
    const float m2x = -2.0f * me.x;
    const float m2y = -2.0f * me.y;
    const float m2z = -2.0f * me.z;
    const float ri = me.w;

    const int jbase = __builtin_amdgcn_readfirstlane(w * JPW);
    const float4* jp = p4  + b * NN + jbase;    // wave-uniform -> s_load
    const float*  jn = n2a + b * NN + jbase;

    float ax = 0.0f, ay = 0.0f, az = 0.0f;

    float4 c[GRP]; float nj[GRP];
    #pragma unroll
    for (int g = 0; g < GRP; ++g) { c[g] = jp[g]; nj[g] = jn[g]; }

#define PROCESS(CC, NJ)                                                    \
    _Pragma("unroll")                                                      \
    for (int g = 0; g < GRP; ++g) {                                        \
        const float sd = fmaf(m2z, CC[g].z,                                \
                         fmaf(m2y, CC[g].y,                                \
                         fmaf(m2x, CC[g].x, NJ[g])));                      \
        const float d2v = sd + n2i;                                        \
        if (__any(d2v < 4.0f)) {                                           \
            const float dist = FAST_SQRT(fmaxf(d2v, 0.0f));                \
            const float tgt  = fmaxf(1.0f, ri + CC[g].w);                  \
            const float p    = fmaxf(tgt - dist, 0.0f);                    \
            const float dx   = fmaf(-0.5f, m2x, -CC[g].x);                 \
            const float dy   = fmaf(-0.5f, m2y, -CC[g].y);                 \
            const float dz   = fmaf(-0.5f, m2z, -CC[g].z);                 \
            ax = fmaf(p, clip1(dx), ax);                                   \
            ay = fmaf(p, clip1(dy), ay);                                   \
            az = fmaf(p, clip1(dz), az);                                   \
        }                                                                  \
    }

    for (int k0 = 0; k0 + GRP < JPW; k0 += GRP) {
        float4 c2[GRP]; float nj2[GRP];
        #pragma unroll
        for (int g = 0; g < GRP; ++g) {     // prefetch next group first
            c2[g]  = jp[k0 + GRP + g];
            nj2[g] = jn[k0 + GRP + g];
        }
        PROCESS(c, nj)
        #pragma unroll
        for (int g = 0; g < GRP; ++g) { c[g] = c2[g]; nj[g] = nj2[g]; }
    }
    PROCESS(c, nj)                          // last group
#undef PROCESS

    sh[w][0][lane] = ax;
    sh[w][1][lane] = ay;
    sh[w][2][lane] = az;
    __syncthreads();

    if (threadIdx.x < 192) {
        const int comp = threadIdx.x >> 6;
        const int ii = threadIdx.x & 63;
        float acc = 0.0f;
        #pragma unroll
        for (int ww = 0; ww < WPB; ++ww)    // ascending w == ascending j
            acc += sh[ww][comp][ii];
        const int o = (b * NN + ibase + ii) * 3 + comp;
        out[o] = fmaf(0.1f / (float)NN, acc, coords[o]);
    }
}

// Fallback if ws too small: correctness backstop.
__global__ __launch_bounds__(256) void ncp_direct(
    const float* __restrict__ coords,
    const float* __restrict__ radii,
    float* __restrict__ out)
{
    __shared__ float4 jt[256];
    const int b = blockIdx.z;
    const int i = blockIdx.x * 256 + threadIdx.x;

    const float xi = coords[(b * NN + i) * 3 + 0];
    const float yi = coords[(b * NN + i) * 3 + 1];
    const float zi = coords[(b * NN + i) * 3 + 2];
    const float ri = radii[b * NN + i];

    float ax = 0.0f, ay = 0.0f, az = 0.0f;

    for (int jc = 0; jc < NN; jc += 256) {
        const int jj = jc + threadIdx.x;
        __syncthreads();
        jt[threadIdx.x] = make_float4(coords[(b * NN + jj) * 3 + 0],
                                      coords[(b * NN + jj) * 3 + 1],
                                      coords[(b * NN + jj) * 3 + 2],
                                      radii[b * NN + jj]);
        __syncthreads();
        #pragma unroll 4
        for (int k = 0; k < 256; ++k) {
            const float4 cc = jt[k];
            const float dx = xi - cc.x;
            const float dy = yi - cc.y;
            const float dz = zi - cc.z;
            const float d2 = fmaf(dx, dx, fmaf(dy, dy, dz * dz));
            if (__any(d2 < 4.0f)) {
                const float dist = FAST_SQRT(d2);
                const float tgt = fmaxf(1.0f, ri + cc.w);
                const float p = fmaxf(tgt - dist, 0.0f);
                ax = fmaf(p, clip1(dx), ax);
                ay = fmaf(p, clip1(dy), ay);
                az = fmaf(p, clip1(dz), az);
            }
        }
    }

    const int o = (b * NN + i) * 3;
    const float sc = 0.1f / (float)NN;
    out[o + 0] = fmaf(sc, ax, coords[o + 0]);
    out[o + 1] = fmaf(sc, ay, coords[o + 1]);
    out[o + 2] = fmaf(sc, az, coords[o + 2]);
}

extern "C" void kernel_launch(void* const* d_in, const int* in_sizes, int n_in,
                              void* d_out, int out_size, void* d_ws, size_t ws_size,
                              hipStream_t stream) {
    const float* coords = (const float*)d_in[0];
    const float* radii  = (const float*)d_in[1];
    float* out = (float*)d_out;
    const size_t need = (size_t)(PACK_ELEMS * 5) * sizeof(float);

    if (ws_size >= need) {
        float4* p4 = (float4*)d_ws;
        float* n2a = (float*)d_ws + N2_OFF;
        ncp_pack<<<(PACK_ELEMS + 255) / 256, 256, 0, stream>>>(coords, radii, p4, n2a);
        ncp_fused<<<dim3(NN / 64, 1, BB), TPB, 0, stream>>>(p4, n2a, coords, out);
    } else {
        ncp_direct<<<dim3(NN / 256, 1, BB), 256, 0, stream>>>(coords, radii, out);
    }
}